// Round 5
// baseline (1196.147 us; speedup 1.0000x reference)
//
#include <hip/hip_runtime.h>

// 2-layer GCN: out = Ahat * ( relu(Ahat * x * W1 + b1) ) * W2 + b2
// Ahat = D^-1/2 (A + I) D^-1/2, aggregation reordered around GEMMs by linearity:
//   layer1: agg first (128-dim), then GEMM (+b1, relu)
//   layer2: GEMM first, then agg (128-dim) (+b2)
// Scatter-free: build CSR-by-dst on device each call, pull-aggregate per node.

static constexpr int IN_DIM   = 128;
static constexpr int HID_DIM  = 256;
static constexpr int OUT_DIMC = 128;

__global__ void k_zero_i32(int* __restrict__ p, int n) {
  int i = blockIdx.x * blockDim.x + threadIdx.x;
  if (i < n) p[i] = 0;
}

__global__ void k_hist(const int* __restrict__ dst, int* __restrict__ cnt, int E) {
  int stride = gridDim.x * blockDim.x;
  for (int e = blockIdx.x * blockDim.x + threadIdx.x; e < E; e += stride)
    atomicAdd(&cnt[dst[e]], 1);
}

__global__ void k_dis(const int* __restrict__ cnt, float* __restrict__ dis, int n) {
  int i = blockIdx.x * blockDim.x + threadIdx.x;
  if (i < n) dis[i] = rsqrtf((float)(cnt[i] + 1));  // +1 = self-loop
}

// ---- exclusive scan of cnt[] over n elements (chunk = 2048 = 256 thr x 8) ----
__global__ void k_chunksum(const int* __restrict__ cnt, int* __restrict__ csum, int n) {
  __shared__ int red[256];
  int tid = threadIdx.x;
  int base = blockIdx.x * 2048;
  int s = 0;
  for (int i = tid; i < 2048; i += 256) {
    int g = base + i;
    if (g < n) s += cnt[g];
  }
  red[tid] = s; __syncthreads();
  for (int off = 128; off > 0; off >>= 1) {
    if (tid < off) red[tid] += red[tid + off];
    __syncthreads();
  }
  if (tid == 0) csum[blockIdx.x] = red[0];
}

__global__ void k_scan_chunks(int* __restrict__ csum, int nchunks) {
  if (blockIdx.x == 0 && threadIdx.x == 0) {
    int acc = 0;
    for (int i = 0; i < nchunks; ++i) { int v = csum[i]; csum[i] = acc; acc += v; }
  }
}

__global__ void k_scan_final(const int* __restrict__ cnt, const int* __restrict__ csum,
                             int* __restrict__ rowp, int* __restrict__ cursor, int n) {
  __shared__ int lds[256];
  int tid = threadIdx.x;
  int gbase = blockIdx.x * 2048 + tid * 8;
  int loc[8]; int s = 0;
#pragma unroll
  for (int j = 0; j < 8; ++j) {
    int g = gbase + j;
    int v = (g < n) ? cnt[g] : 0;
    loc[j] = v; s += v;
  }
  lds[tid] = s; __syncthreads();
  for (int off = 1; off < 256; off <<= 1) {
    int add = (tid >= off) ? lds[tid - off] : 0;
    __syncthreads();
    lds[tid] += add;
    __syncthreads();
  }
  int run = csum[blockIdx.x] + lds[tid] - s;  // exclusive prefix for this thread
#pragma unroll
  for (int j = 0; j < 8; ++j) {
    int g = gbase + j;
    if (g < n) { rowp[g] = run; cursor[g] = run; }
    run += loc[j];
  }
}

__global__ void k_scatter(const int* __restrict__ src, const int* __restrict__ dst,
                          int* __restrict__ cursor, int* __restrict__ csr, int E) {
  int stride = gridDim.x * blockDim.x;
  for (int e = blockIdx.x * blockDim.x + threadIdx.x; e < E; e += stride) {
    int p = atomicAdd(&cursor[dst[e]], 1);
    csr[p] = src[e];
  }
}

// ---- pull aggregation: one wave per dst node, D=128 (64 lanes x float2) ----
// out[d] = dis[d] * ( sum_{s in N(d)} dis[s]*feat[s] + dis[d]*feat[d] ) + bias
template<int D>
__global__ void k_agg(const float* __restrict__ feat, const float* __restrict__ dis,
                      const int* __restrict__ rowp, const int* __restrict__ cnt,
                      const int* __restrict__ csr, float* __restrict__ outp,
                      const float* __restrict__ bias, int n) {
  int wave = (blockIdx.x * blockDim.x + threadIdx.x) >> 6;
  int lane = threadIdx.x & 63;
  if (wave >= n) return;
  const int d = wave;
  const float dd = dis[d];
  const int base = rowp[d];
  const int deg = cnt[d];
  const float2* f2 = (const float2*)feat;
  float2 self = f2[(size_t)d * (D / 2) + lane];
  float ax = dd * self.x, ay = dd * self.y;
  for (int c = 0; c < deg; c += 64) {
    int idx = c + lane;
    int s_l = 0; float w_l = 0.f;
    if (idx < deg) { s_l = csr[base + idx]; w_l = dis[s_l]; }
    int m = deg - c; if (m > 64) m = 64;
    for (int j = 0; j < m; ++j) {
      int sj = __shfl(s_l, j);
      float wj = __shfl(w_l, j);
      float2 v = f2[(size_t)sj * (D / 2) + lane];
      ax = fmaf(wj, v.x, ax);
      ay = fmaf(wj, v.y, ay);
    }
  }
  ax *= dd; ay *= dd;
  if (bias) { ax += bias[lane * 2]; ay += bias[lane * 2 + 1]; }
  float2 o; o.x = ax; o.y = ay;
  ((float2*)outp)[(size_t)d * (D / 2) + lane] = o;
}

// ---- fp32 tiled GEMM: C[M,N] = A[M,K] @ B[K,N] (+bias, optional relu) ----
template<int K, bool RELU>
__global__ __launch_bounds__(256) void k_gemm(const float* __restrict__ A,
                                              const float* __restrict__ B,
                                              const float* __restrict__ bias,
                                              float* __restrict__ C,
                                              int M, int N) {
  constexpr int BM = 64, BN = 64, BK = 32;
  __shared__ float As[BK][BM + 4];  // +4 pad keeps float4 reads aligned, breaks bank stride
  __shared__ float Bs[BK][BN];
  int colTiles = N >> 6;
  int bx = blockIdx.x % colTiles;
  int by = blockIdx.x / colTiles;
  int tid = threadIdx.x;
  int tx = tid & 15, ty = tid >> 4;
  int row0 = by * BM, col0 = bx * BN;
  float acc[4][4] = {};
  for (int k0 = 0; k0 < K; k0 += BK) {
#pragma unroll
    for (int i = 0; i < 2; ++i) {
      int t = tid + i * 256;
      int a_r = t >> 3;           // 0..63
      int a_c = (t & 7) << 2;     // 0,4,...,28
      int r = row0 + a_r;
      float4 v = make_float4(0.f, 0.f, 0.f, 0.f);
      if (r < M) v = *(const float4*)&A[(size_t)r * K + k0 + a_c];
      As[a_c + 0][a_r] = v.x;
      As[a_c + 1][a_r] = v.y;
      As[a_c + 2][a_r] = v.z;
      As[a_c + 3][a_r] = v.w;
    }
#pragma unroll
    for (int i = 0; i < 2; ++i) {
      int t = tid + i * 256;
      int b_r = t >> 4;           // 0..31
      int b_c = (t & 15) << 2;
      *(float4*)&Bs[b_r][b_c] = *(const float4*)&B[(size_t)(k0 + b_r) * N + col0 + b_c];
    }
    __syncthreads();
#pragma unroll
    for (int k = 0; k < BK; ++k) {
      float a[4], b[4];
#pragma unroll
      for (int i = 0; i < 4; ++i) a[i] = As[k][ty * 4 + i];
#pragma unroll
      for (int j = 0; j < 4; ++j) b[j] = Bs[k][tx * 4 + j];
#pragma unroll
      for (int i = 0; i < 4; ++i)
#pragma unroll
        for (int j = 0; j < 4; ++j)
          acc[i][j] = fmaf(a[i], b[j], acc[i][j]);
    }
    __syncthreads();
  }
  float bc[4] = {0.f, 0.f, 0.f, 0.f};
  if (bias) {
#pragma unroll
    for (int j = 0; j < 4; ++j) bc[j] = bias[col0 + tx * 4 + j];
  }
#pragma unroll
  for (int i = 0; i < 4; ++i) {
    int r = row0 + ty * 4 + i;
    if (r < M) {
      float v0 = acc[i][0] + bc[0];
      float v1 = acc[i][1] + bc[1];
      float v2 = acc[i][2] + bc[2];
      float v3 = acc[i][3] + bc[3];
      if (RELU) {
        v0 = fmaxf(v0, 0.f); v1 = fmaxf(v1, 0.f);
        v2 = fmaxf(v2, 0.f); v3 = fmaxf(v3, 0.f);
      }
      *(float4*)&C[(size_t)r * N + col0 + tx * 4] = make_float4(v0, v1, v2, v3);
    }
  }
}

extern "C" void kernel_launch(void* const* d_in, const int* in_sizes, int n_in,
                              void* d_out, int out_size, void* d_ws, size_t ws_size,
                              hipStream_t stream) {
  const float* x  = (const float*)d_in[0];
  const int*   ei = (const int*)d_in[1];
  const float* W1 = (const float*)d_in[2];
  const float* b1 = (const float*)d_in[3];
  const float* W2 = (const float*)d_in[4];
  const float* b2 = (const float*)d_in[5];
  float* out = (float*)d_out;

  const int n = in_sizes[0] / IN_DIM;
  const int E = in_sizes[1] / 2;
  const int* src = ei;
  const int* dst = ei + E;

  // workspace carve-up
  char* ws = (char*)d_ws;
  size_t off = 0;
  auto alloc = [&](size_t bytes) -> char* {
    char* p = ws + off;
    off = (off + bytes + 255) & ~size_t(255);
    return p;
  };
  int*   cnt    = (int*)  alloc((size_t)n * 4);
  int*   rowp   = (int*)  alloc((size_t)n * 4);
  int*   cursor = (int*)  alloc((size_t)n * 4);
  float* dis    = (float*)alloc((size_t)n * 4);
  int*   csum   = (int*)  alloc(4096);
  int*   csr    = (int*)  alloc((size_t)E * 4);
  float* B1     = (float*)alloc((size_t)n * IN_DIM * 4);   // agg_x, later hw
  float* B2     = (float*)alloc((size_t)n * HID_DIM * 4);  // h

  const int nb = (n + 255) / 256;
  const int nchunks = (n + 2047) / 2048;

  // ---- degree + dis + CSR build ----
  k_zero_i32<<<nb, 256, 0, stream>>>(cnt, n);
  k_hist<<<2048, 256, 0, stream>>>(dst, cnt, E);
  k_dis<<<nb, 256, 0, stream>>>(cnt, dis, n);
  k_chunksum<<<nchunks, 256, 0, stream>>>(cnt, csum, n);
  k_scan_chunks<<<1, 1, 0, stream>>>(csum, nchunks);
  k_scan_final<<<nchunks, 256, 0, stream>>>(cnt, csum, rowp, cursor, n);
  k_scatter<<<2048, 256, 0, stream>>>(src, dst, cursor, csr, E);

  // ---- layer 1: agg(x) -> B1; B2 = relu(B1 @ W1 + b1) ----
  k_agg<IN_DIM><<<(n + 3) / 4, 256, 0, stream>>>(x, dis, rowp, cnt, csr, B1, nullptr, n);
  {
    int rowTiles = (n + 63) / 64, colTiles = HID_DIM / 64;
    k_gemm<IN_DIM, true><<<rowTiles * colTiles, 256, 0, stream>>>(B1, W1, b1, B2, n, HID_DIM);
  }
  // ---- layer 2: B1 = B2 @ W2; out = agg(B1) + b2 ----
  {
    int rowTiles = (n + 63) / 64, colTiles = OUT_DIMC / 64;
    k_gemm<HID_DIM, false><<<rowTiles * colTiles, 256, 0, stream>>>(B2, W2, nullptr, B1, n, OUT_DIMC);
  }
  k_agg<OUT_DIMC><<<(n + 3) / 4, 256, 0, stream>>>(B1, dis, rowp, cnt, csr, out, b2, n);
}

// Round 7
// 1038.183 us; speedup vs baseline: 1.1522x; 1.1522x over previous
//
#include <hip/hip_runtime.h>

// 2-layer GCN: out = Ahat * ( relu(Ahat * x * W1 + b1) ) * W2 + b2
// Ahat = D^-1/2 (A + I) D^-1/2, aggregation reordered around GEMMs by linearity.
// Scatter-free aggregation via CSR-by-dst built on device each call.
// R5 change: k_hist / k_scatter partitioned by dst-range with range = blockIdx&7
// (XCD round-robin heuristic) so csr/cursor/cnt cache lines are owned by a
// single XCD L2 -> kills the ~16x cross-XCD write-back amplification seen in
// rocprof (WRITE_SIZE 196 MB for a 12.8 MB csr array).

static constexpr int IN_DIM   = 128;
static constexpr int HID_DIM  = 256;
static constexpr int OUT_DIMC = 128;
static constexpr int NGROUP   = 8;   // = #XCDs on MI355X

__global__ void k_zero_i32(int* __restrict__ p, int n) {
  int i = blockIdx.x * blockDim.x + threadIdx.x;
  if (i < n) p[i] = 0;
}

// dst-range-partitioned histogram: group g = blockIdx&7 only touches cnt lines
// in its node range -> atomics stay in one XCD's L2.
__global__ void k_hist(const int* __restrict__ dst, int* __restrict__ cnt,
                       int E, int n) {
  int g = blockIdx.x & (NGROUP - 1);
  int b = blockIdx.x >> 3;                 // block index within group
  int bpg = gridDim.x >> 3;                // blocks per group
  int lo = (int)((long long)n * g / NGROUP);
  int hi = (int)((long long)n * (g + 1) / NGROUP);
  int stride = bpg * blockDim.x;
  for (int e = b * blockDim.x + threadIdx.x; e < E; e += stride) {
    int d = dst[e];
    if (d >= lo && d < hi) atomicAdd(&cnt[d], 1);
  }
}

__global__ void k_dis(const int* __restrict__ cnt, float* __restrict__ dis, int n) {
  int i = blockIdx.x * blockDim.x + threadIdx.x;
  if (i < n) dis[i] = rsqrtf((float)(cnt[i] + 1));  // +1 = self-loop
}

// ---- exclusive scan of cnt[] over n elements (chunk = 2048 = 256 thr x 8) ----
__global__ void k_chunksum(const int* __restrict__ cnt, int* __restrict__ csum, int n) {
  __shared__ int red[256];
  int tid = threadIdx.x;
  int base = blockIdx.x * 2048;
  int s = 0;
  for (int i = tid; i < 2048; i += 256) {
    int g = base + i;
    if (g < n) s += cnt[g];
  }
  red[tid] = s; __syncthreads();
  for (int off = 128; off > 0; off >>= 1) {
    if (tid < off) red[tid] += red[tid + off];
    __syncthreads();
  }
  if (tid == 0) csum[blockIdx.x] = red[0];
}

__global__ void k_scan_chunks(int* __restrict__ csum, int nchunks) {
  if (blockIdx.x == 0 && threadIdx.x == 0) {
    int acc = 0;
    for (int i = 0; i < nchunks; ++i) { int v = csum[i]; csum[i] = acc; acc += v; }
  }
}

__global__ void k_scan_final(const int* __restrict__ cnt, const int* __restrict__ csum,
                             int* __restrict__ rowp, int* __restrict__ cursor, int n) {
  __shared__ int lds[256];
  int tid = threadIdx.x;
  int gbase = blockIdx.x * 2048 + tid * 8;
  int loc[8]; int s = 0;
#pragma unroll
  for (int j = 0; j < 8; ++j) {
    int g = gbase + j;
    int v = (g < n) ? cnt[g] : 0;
    loc[j] = v; s += v;
  }
  lds[tid] = s; __syncthreads();
  for (int off = 1; off < 256; off <<= 1) {
    int add = (tid >= off) ? lds[tid - off] : 0;
    __syncthreads();
    lds[tid] += add;
    __syncthreads();
  }
  int run = csum[blockIdx.x] + lds[tid] - s;  // exclusive prefix for this thread
#pragma unroll
  for (int j = 0; j < 8; ++j) {
    int g = gbase + j;
    if (g < n) { rowp[g] = run; cursor[g] = run; }
    run += loc[j];
  }
}

// dst-range-partitioned bucket scatter: group g writes only csr/cursor lines in
// its node range. Each group re-scans the full edge list (streaming, cheap).
__global__ void k_scatter(const int* __restrict__ src, const int* __restrict__ dst,
                          int* __restrict__ cursor, int* __restrict__ csr,
                          int E, int n) {
  int g = blockIdx.x & (NGROUP - 1);
  int b = blockIdx.x >> 3;
  int bpg = gridDim.x >> 3;
  int lo = (int)((long long)n * g / NGROUP);
  int hi = (int)((long long)n * (g + 1) / NGROUP);
  int stride = bpg * blockDim.x;
  for (int e = b * blockDim.x + threadIdx.x; e < E; e += stride) {
    int d = dst[e];
    if (d >= lo && d < hi) {
      int p = atomicAdd(&cursor[d], 1);
      csr[p] = src[e];
    }
  }
}

// ---- pull aggregation: one wave per dst node, D=128 (64 lanes x float2) ----
// out[d] = dis[d] * ( sum_{s in N(d)} dis[s]*feat[s] + dis[d]*feat[d] ) + bias
template<int D>
__global__ void k_agg(const float* __restrict__ feat, const float* __restrict__ dis,
                      const int* __restrict__ rowp, const int* __restrict__ cnt,
                      const int* __restrict__ csr, float* __restrict__ outp,
                      const float* __restrict__ bias, int n) {
  int wave = (blockIdx.x * blockDim.x + threadIdx.x) >> 6;
  int lane = threadIdx.x & 63;
  if (wave >= n) return;
  const int d = wave;
  const float dd = dis[d];
  const int base = rowp[d];
  const int deg = cnt[d];
  const float2* f2 = (const float2*)feat;
  float2 self = f2[(size_t)d * (D / 2) + lane];
  float ax = dd * self.x, ay = dd * self.y;
  for (int c = 0; c < deg; c += 64) {
    int idx = c + lane;
    int s_l = 0; float w_l = 0.f;
    if (idx < deg) { s_l = csr[base + idx]; w_l = dis[s_l]; }
    int m = deg - c; if (m > 64) m = 64;
    for (int j = 0; j < m; ++j) {
      int sj = __shfl(s_l, j);
      float wj = __shfl(w_l, j);
      float2 v = f2[(size_t)sj * (D / 2) + lane];
      ax = fmaf(wj, v.x, ax);
      ay = fmaf(wj, v.y, ay);
    }
  }
  ax *= dd; ay *= dd;
  if (bias) { ax += bias[lane * 2]; ay += bias[lane * 2 + 1]; }
  float2 o; o.x = ax; o.y = ay;
  ((float2*)outp)[(size_t)d * (D / 2) + lane] = o;
}

// ---- fp32 tiled GEMM: C[M,N] = A[M,K] @ B[K,N] (+bias, optional relu) ----
template<int K, bool RELU>
__global__ __launch_bounds__(256) void k_gemm(const float* __restrict__ A,
                                              const float* __restrict__ B,
                                              const float* __restrict__ bias,
                                              float* __restrict__ C,
                                              int M, int N) {
  constexpr int BM = 64, BN = 64, BK = 32;
  __shared__ float As[BK][BM + 4];
  __shared__ float Bs[BK][BN];
  int colTiles = N >> 6;
  int bx = blockIdx.x % colTiles;
  int by = blockIdx.x / colTiles;
  int tid = threadIdx.x;
  int tx = tid & 15, ty = tid >> 4;
  int row0 = by * BM, col0 = bx * BN;
  float acc[4][4] = {};
  for (int k0 = 0; k0 < K; k0 += BK) {
#pragma unroll
    for (int i = 0; i < 2; ++i) {
      int t = tid + i * 256;
      int a_r = t >> 3;           // 0..63
      int a_c = (t & 7) << 2;     // 0,4,...,28
      int r = row0 + a_r;
      float4 v = make_float4(0.f, 0.f, 0.f, 0.f);
      if (r < M) v = *(const float4*)&A[(size_t)r * K + k0 + a_c];
      As[a_c + 0][a_r] = v.x;
      As[a_c + 1][a_r] = v.y;
      As[a_c + 2][a_r] = v.z;
      As[a_c + 3][a_r] = v.w;
    }
#pragma unroll
    for (int i = 0; i < 2; ++i) {
      int t = tid + i * 256;
      int b_r = t >> 4;           // 0..31
      int b_c = (t & 15) << 2;
      *(float4*)&Bs[b_r][b_c] = *(const float4*)&B[(size_t)(k0 + b_r) * N + col0 + b_c];
    }
    __syncthreads();
#pragma unroll
    for (int k = 0; k < BK; ++k) {
      float a[4], b[4];
#pragma unroll
      for (int i = 0; i < 4; ++i) a[i] = As[k][ty * 4 + i];
#pragma unroll
      for (int j = 0; j < 4; ++j) b[j] = Bs[k][tx * 4 + j];
#pragma unroll
      for (int i = 0; i < 4; ++i)
#pragma unroll
        for (int j = 0; j < 4; ++j)
          acc[i][j] = fmaf(a[i], b[j], acc[i][j]);
    }
    __syncthreads();
  }
  float bc[4] = {0.f, 0.f, 0.f, 0.f};
  if (bias) {
#pragma unroll
    for (int j = 0; j < 4; ++j) bc[j] = bias[col0 + tx * 4 + j];
  }
#pragma unroll
  for (int i = 0; i < 4; ++i) {
    int r = row0 + ty * 4 + i;
    if (r < M) {
      float v0 = acc[i][0] + bc[0];
      float v1 = acc[i][1] + bc[1];
      float v2 = acc[i][2] + bc[2];
      float v3 = acc[i][3] + bc[3];
      if (RELU) {
        v0 = fmaxf(v0, 0.f); v1 = fmaxf(v1, 0.f);
        v2 = fmaxf(v2, 0.f); v3 = fmaxf(v3, 0.f);
      }
      *(float4*)&C[(size_t)r * N + col0 + tx * 4] = make_float4(v0, v1, v2, v3);
    }
  }
}

extern "C" void kernel_launch(void* const* d_in, const int* in_sizes, int n_in,
                              void* d_out, int out_size, void* d_ws, size_t ws_size,
                              hipStream_t stream) {
  const float* x  = (const float*)d_in[0];
  const int*   ei = (const int*)d_in[1];
  const float* W1 = (const float*)d_in[2];
  const float* b1 = (const float*)d_in[3];
  const float* W2 = (const float*)d_in[4];
  const float* b2 = (const float*)d_in[5];
  float* out = (float*)d_out;

  const int n = in_sizes[0] / IN_DIM;
  const int E = in_sizes[1] / 2;
  const int* src = ei;
  const int* dst = ei + E;

  // workspace carve-up
  char* ws = (char*)d_ws;
  size_t off = 0;
  auto alloc = [&](size_t bytes) -> char* {
    char* p = ws + off;
    off = (off + bytes + 255) & ~size_t(255);
    return p;
  };
  int*   cnt    = (int*)  alloc((size_t)n * 4);
  int*   rowp   = (int*)  alloc((size_t)n * 4);
  int*   cursor = (int*)  alloc((size_t)n * 4);
  float* dis    = (float*)alloc((size_t)n * 4);
  int*   csum   = (int*)  alloc(4096);
  int*   csr    = (int*)  alloc((size_t)E * 4);
  float* B1     = (float*)alloc((size_t)n * IN_DIM * 4);   // agg_x, later hw
  float* B2     = (float*)alloc((size_t)n * HID_DIM * 4);  // h

  const int nb = (n + 255) / 256;
  const int nchunks = (n + 2047) / 2048;

  // ---- degree + dis + CSR build (dst-range partitioned, XCD-local) ----
  k_zero_i32<<<nb, 256, 0, stream>>>(cnt, n);
  k_hist<<<2048, 256, 0, stream>>>(dst, cnt, E, n);
  k_dis<<<nb, 256, 0, stream>>>(cnt, dis, n);
  k_chunksum<<<nchunks, 256, 0, stream>>>(cnt, csum, n);
  k_scan_chunks<<<1, 1, 0, stream>>>(csum, nchunks);
  k_scan_final<<<nchunks, 256, 0, stream>>>(cnt, csum, rowp, cursor, n);
  k_scatter<<<2048, 256, 0, stream>>>(src, dst, cursor, csr, E, n);

  // ---- layer 1: agg(x) -> B1; B2 = relu(B1 @ W1 + b1) ----
  k_agg<IN_DIM><<<(n + 3) / 4, 256, 0, stream>>>(x, dis, rowp, cnt, csr, B1, nullptr, n);
  {
    int rowTiles = (n + 63) / 64, colTiles = HID_DIM / 64;
    k_gemm<IN_DIM, true><<<rowTiles * colTiles, 256, 0, stream>>>(B1, W1, b1, B2, n, HID_DIM);
  }
  // ---- layer 2: B1 = B2 @ W2; out = agg(B1) + b2 ----
  {
    int rowTiles = (n + 63) / 64, colTiles = OUT_DIMC / 64;
    k_gemm<HID_DIM, false><<<rowTiles * colTiles, 256, 0, stream>>>(B2, W2, nullptr, B1, n, OUT_DIMC);
  }
  k_agg<OUT_DIMC><<<(n + 3) / 4, 256, 0, stream>>>(B1, dis, rowp, cnt, csr, out, b2, n);
}

// Round 8
// 1013.732 us; speedup vs baseline: 1.1799x; 1.0241x over previous
//
#include <hip/hip_runtime.h>

// 2-layer GCN: out = Ahat * ( relu(Ahat * x * W1 + b1) ) * W2 + b2
// Ahat = D^-1/2 (A + I) D^-1/2, aggregation reordered around GEMMs by linearity.
// Scatter-free aggregation via CSR-by-dst built on device each call.
// R5: k_hist/k_scatter dst-range partitioned (blockIdx&7 ~ XCD) -> fixed 16x
//     write amplification (WRITE_SIZE 196MB -> gone from top-5).
// R7: k_agg restructured for memory-level parallelism: half-wave float4 rows
//     (2 edges in flight per iteration) + unroll-4 -> attack the 45 cy/edge
//     latency bound seen in rocprof (VALUBusy 17%, 44% BW).

static constexpr int IN_DIM   = 128;
static constexpr int HID_DIM  = 256;
static constexpr int OUT_DIMC = 128;
static constexpr int NGROUP   = 8;   // = #XCDs on MI355X

__global__ void k_zero_i32(int* __restrict__ p, int n) {
  int i = blockIdx.x * blockDim.x + threadIdx.x;
  if (i < n) p[i] = 0;
}

// dst-range-partitioned histogram: group g = blockIdx&7 only touches cnt lines
// in its node range -> atomics stay in one XCD's L2.
__global__ void k_hist(const int* __restrict__ dst, int* __restrict__ cnt,
                       int E, int n) {
  int g = blockIdx.x & (NGROUP - 1);
  int b = blockIdx.x >> 3;                 // block index within group
  int bpg = gridDim.x >> 3;                // blocks per group
  int lo = (int)((long long)n * g / NGROUP);
  int hi = (int)((long long)n * (g + 1) / NGROUP);
  int stride = bpg * blockDim.x;
  for (int e = b * blockDim.x + threadIdx.x; e < E; e += stride) {
    int d = dst[e];
    if (d >= lo && d < hi) atomicAdd(&cnt[d], 1);
  }
}

__global__ void k_dis(const int* __restrict__ cnt, float* __restrict__ dis, int n) {
  int i = blockIdx.x * blockDim.x + threadIdx.x;
  if (i < n) dis[i] = rsqrtf((float)(cnt[i] + 1));  // +1 = self-loop
}

// ---- exclusive scan of cnt[] over n elements (chunk = 2048 = 256 thr x 8) ----
__global__ void k_chunksum(const int* __restrict__ cnt, int* __restrict__ csum, int n) {
  __shared__ int red[256];
  int tid = threadIdx.x;
  int base = blockIdx.x * 2048;
  int s = 0;
  for (int i = tid; i < 2048; i += 256) {
    int g = base + i;
    if (g < n) s += cnt[g];
  }
  red[tid] = s; __syncthreads();
  for (int off = 128; off > 0; off >>= 1) {
    if (tid < off) red[tid] += red[tid + off];
    __syncthreads();
  }
  if (tid == 0) csum[blockIdx.x] = red[0];
}

__global__ void k_scan_chunks(int* __restrict__ csum, int nchunks) {
  if (blockIdx.x == 0 && threadIdx.x == 0) {
    int acc = 0;
    for (int i = 0; i < nchunks; ++i) { int v = csum[i]; csum[i] = acc; acc += v; }
  }
}

__global__ void k_scan_final(const int* __restrict__ cnt, const int* __restrict__ csum,
                             int* __restrict__ rowp, int* __restrict__ cursor, int n) {
  __shared__ int lds[256];
  int tid = threadIdx.x;
  int gbase = blockIdx.x * 2048 + tid * 8;
  int loc[8]; int s = 0;
#pragma unroll
  for (int j = 0; j < 8; ++j) {
    int g = gbase + j;
    int v = (g < n) ? cnt[g] : 0;
    loc[j] = v; s += v;
  }
  lds[tid] = s; __syncthreads();
  for (int off = 1; off < 256; off <<= 1) {
    int add = (tid >= off) ? lds[tid - off] : 0;
    __syncthreads();
    lds[tid] += add;
    __syncthreads();
  }
  int run = csum[blockIdx.x] + lds[tid] - s;  // exclusive prefix for this thread
#pragma unroll
  for (int j = 0; j < 8; ++j) {
    int g = gbase + j;
    if (g < n) { rowp[g] = run; cursor[g] = run; }
    run += loc[j];
  }
}

// dst-range-partitioned bucket scatter: group g writes only csr/cursor lines in
// its node range. Each group re-scans the full edge list (streaming, cheap).
__global__ void k_scatter(const int* __restrict__ src, const int* __restrict__ dst,
                          int* __restrict__ cursor, int* __restrict__ csr,
                          int E, int n) {
  int g = blockIdx.x & (NGROUP - 1);
  int b = blockIdx.x >> 3;
  int bpg = gridDim.x >> 3;
  int lo = (int)((long long)n * g / NGROUP);
  int hi = (int)((long long)n * (g + 1) / NGROUP);
  int stride = bpg * blockDim.x;
  for (int e = b * blockDim.x + threadIdx.x; e < E; e += stride) {
    int d = dst[e];
    if (d >= lo && d < hi) {
      int p = atomicAdd(&cursor[d], 1);
      csr[p] = src[e];
    }
  }
}

// ---- pull aggregation, MLP version: one wave per dst node, D=128.
// Half-wave layout: lanes 0-31 and 32-63 each cover a full 512B row as float4,
// processing 2 edges per iteration (doubles rows in flight); unroll-4 gives
// up to 8 outstanding gathers per wave. Halves' partials combined via
// __shfl_xor(.,32) at the end; half 0 writes the row.
template<int D>
__global__ void k_agg(const float* __restrict__ feat, const float* __restrict__ dis,
                      const int* __restrict__ rowp, const int* __restrict__ cnt,
                      const int* __restrict__ csr, float* __restrict__ outp,
                      const float* __restrict__ bias, int n) {
  constexpr int Q = D / 4;               // float4s per row (32 for D=128)
  int wid = (blockIdx.x * blockDim.x + threadIdx.x) >> 6;
  if (wid >= n) return;
  const int lane = threadIdx.x & 63;
  const int half = lane >> 5;            // which edge of the pair
  const int q    = lane & 31;            // float4 index within row
  const int d    = wid;
  const float dd = dis[d];
  const int base = rowp[d];
  const int deg  = cnt[d];
  const float4* f4 = (const float4*)feat;

  float4 acc = make_float4(0.f, 0.f, 0.f, 0.f);
  if (half == 0) {                       // self-loop term (half 1 contributes 0)
    float4 s4 = f4[(size_t)d * Q + q];
    acc.x = dd * s4.x; acc.y = dd * s4.y; acc.z = dd * s4.z; acc.w = dd * s4.w;
  }

  for (int c = 0; c < deg; c += 64) {
    int idx = c + lane;
    int s_l = 0; float w_l = 0.f;
    if (idx < deg) { s_l = csr[base + idx]; w_l = dis[s_l]; }
    int m = deg - c; if (m > 64) m = 64;
    int pairs = (m + 1) >> 1;            // lanes beyond m have w_l=0 -> safe
#pragma unroll 4
    for (int j = 0; j < pairs; ++j) {
      int ei = 2 * j + half;
      int   sj = __shfl(s_l, ei);
      float wj = __shfl(w_l, ei);
      float4 v = f4[(size_t)sj * Q + q];
      acc.x = fmaf(wj, v.x, acc.x);
      acc.y = fmaf(wj, v.y, acc.y);
      acc.z = fmaf(wj, v.z, acc.z);
      acc.w = fmaf(wj, v.w, acc.w);
    }
  }

  // combine the two halves' partial sums
  acc.x += __shfl_xor(acc.x, 32);
  acc.y += __shfl_xor(acc.y, 32);
  acc.z += __shfl_xor(acc.z, 32);
  acc.w += __shfl_xor(acc.w, 32);

  if (half == 0) {
    acc.x *= dd; acc.y *= dd; acc.z *= dd; acc.w *= dd;
    if (bias) {
      float4 b4 = ((const float4*)bias)[q];
      acc.x += b4.x; acc.y += b4.y; acc.z += b4.z; acc.w += b4.w;
    }
    ((float4*)outp)[(size_t)d * Q + q] = acc;
  }
}

// ---- fp32 tiled GEMM: C[M,N] = A[M,K] @ B[K,N] (+bias, optional relu) ----
template<int K, bool RELU>
__global__ __launch_bounds__(256) void k_gemm(const float* __restrict__ A,
                                              const float* __restrict__ B,
                                              const float* __restrict__ bias,
                                              float* __restrict__ C,
                                              int M, int N) {
  constexpr int BM = 64, BN = 64, BK = 32;
  __shared__ float As[BK][BM + 4];
  __shared__ float Bs[BK][BN];
  int colTiles = N >> 6;
  int bx = blockIdx.x % colTiles;
  int by = blockIdx.x / colTiles;
  int tid = threadIdx.x;
  int tx = tid & 15, ty = tid >> 4;
  int row0 = by * BM, col0 = bx * BN;
  float acc[4][4] = {};
  for (int k0 = 0; k0 < K; k0 += BK) {
#pragma unroll
    for (int i = 0; i < 2; ++i) {
      int t = tid + i * 256;
      int a_r = t >> 3;           // 0..63
      int a_c = (t & 7) << 2;     // 0,4,...,28
      int r = row0 + a_r;
      float4 v = make_float4(0.f, 0.f, 0.f, 0.f);
      if (r < M) v = *(const float4*)&A[(size_t)r * K + k0 + a_c];
      As[a_c + 0][a_r] = v.x;
      As[a_c + 1][a_r] = v.y;
      As[a_c + 2][a_r] = v.z;
      As[a_c + 3][a_r] = v.w;
    }
#pragma unroll
    for (int i = 0; i < 2; ++i) {
      int t = tid + i * 256;
      int b_r = t >> 4;           // 0..31
      int b_c = (t & 15) << 2;
      *(float4*)&Bs[b_r][b_c] = *(const float4*)&B[(size_t)(k0 + b_r) * N + col0 + b_c];
    }
    __syncthreads();
#pragma unroll
    for (int k = 0; k < BK; ++k) {
      float a[4], b[4];
#pragma unroll
      for (int i = 0; i < 4; ++i) a[i] = As[k][ty * 4 + i];
#pragma unroll
      for (int j = 0; j < 4; ++j) b[j] = Bs[k][tx * 4 + j];
#pragma unroll
      for (int i = 0; i < 4; ++i)
#pragma unroll
        for (int j = 0; j < 4; ++j)
          acc[i][j] = fmaf(a[i], b[j], acc[i][j]);
    }
    __syncthreads();
  }
  float bc[4] = {0.f, 0.f, 0.f, 0.f};
  if (bias) {
#pragma unroll
    for (int j = 0; j < 4; ++j) bc[j] = bias[col0 + tx * 4 + j];
  }
#pragma unroll
  for (int i = 0; i < 4; ++i) {
    int r = row0 + ty * 4 + i;
    if (r < M) {
      float v0 = acc[i][0] + bc[0];
      float v1 = acc[i][1] + bc[1];
      float v2 = acc[i][2] + bc[2];
      float v3 = acc[i][3] + bc[3];
      if (RELU) {
        v0 = fmaxf(v0, 0.f); v1 = fmaxf(v1, 0.f);
        v2 = fmaxf(v2, 0.f); v3 = fmaxf(v3, 0.f);
      }
      *(float4*)&C[(size_t)r * N + col0 + tx * 4] = make_float4(v0, v1, v2, v3);
    }
  }
}

extern "C" void kernel_launch(void* const* d_in, const int* in_sizes, int n_in,
                              void* d_out, int out_size, void* d_ws, size_t ws_size,
                              hipStream_t stream) {
  const float* x  = (const float*)d_in[0];
  const int*   ei = (const int*)d_in[1];
  const float* W1 = (const float*)d_in[2];
  const float* b1 = (const float*)d_in[3];
  const float* W2 = (const float*)d_in[4];
  const float* b2 = (const float*)d_in[5];
  float* out = (float*)d_out;

  const int n = in_sizes[0] / IN_DIM;
  const int E = in_sizes[1] / 2;
  const int* src = ei;
  const int* dst = ei + E;

  // workspace carve-up
  char* ws = (char*)d_ws;
  size_t off = 0;
  auto alloc = [&](size_t bytes) -> char* {
    char* p = ws + off;
    off = (off + bytes + 255) & ~size_t(255);
    return p;
  };
  int*   cnt    = (int*)  alloc((size_t)n * 4);
  int*   rowp   = (int*)  alloc((size_t)n * 4);
  int*   cursor = (int*)  alloc((size_t)n * 4);
  float* dis    = (float*)alloc((size_t)n * 4);
  int*   csum   = (int*)  alloc(4096);
  int*   csr    = (int*)  alloc((size_t)E * 4);
  float* B1     = (float*)alloc((size_t)n * IN_DIM * 4);   // agg_x, later hw
  float* B2     = (float*)alloc((size_t)n * HID_DIM * 4);  // h

  const int nb = (n + 255) / 256;
  const int nchunks = (n + 2047) / 2048;

  // ---- degree + dis + CSR build (dst-range partitioned, XCD-local) ----
  k_zero_i32<<<nb, 256, 0, stream>>>(cnt, n);
  k_hist<<<2048, 256, 0, stream>>>(dst, cnt, E, n);
  k_dis<<<nb, 256, 0, stream>>>(cnt, dis, n);
  k_chunksum<<<nchunks, 256, 0, stream>>>(cnt, csum, n);
  k_scan_chunks<<<1, 1, 0, stream>>>(csum, nchunks);
  k_scan_final<<<nchunks, 256, 0, stream>>>(cnt, csum, rowp, cursor, n);
  k_scatter<<<2048, 256, 0, stream>>>(src, dst, cursor, csr, E, n);

  // ---- layer 1: agg(x) -> B1; B2 = relu(B1 @ W1 + b1) ----
  k_agg<IN_DIM><<<(n + 3) / 4, 256, 0, stream>>>(x, dis, rowp, cnt, csr, B1, nullptr, n);
  {
    int rowTiles = (n + 63) / 64, colTiles = HID_DIM / 64;
    k_gemm<IN_DIM, true><<<rowTiles * colTiles, 256, 0, stream>>>(B1, W1, b1, B2, n, HID_DIM);
  }
  // ---- layer 2: B1 = B2 @ W2; out = agg(B1) + b2 ----
  {
    int rowTiles = (n + 63) / 64, colTiles = OUT_DIMC / 64;
    k_gemm<HID_DIM, false><<<rowTiles * colTiles, 256, 0, stream>>>(B2, W2, nullptr, B1, n, OUT_DIMC);
  }
  k_agg<OUT_DIMC><<<(n + 3) / 4, 256, 0, stream>>>(B1, dis, rowp, cnt, csr, out, b2, n);
}

// Round 9
// 809.371 us; speedup vs baseline: 1.4779x; 1.2525x over previous
//
#include <hip/hip_runtime.h>

// 2-layer GCN: out = Ahat * ( relu(Ahat * x * W1 + b1) ) * W2 + b2
// R5: k_hist/k_scatter dst-range partitioned (blockIdx&7 ~ XCD) -> killed 16x
//     cross-XCD write amplification.
// R7: k_agg half-wave float4 MLP -> only +7%; rocprof shows agg at random-
//     gather fabric ceiling (3.8 TB/s, FETCH 798MB of 1.69GB logical).
// R9: halve gather traffic: gather tables in bf16 (x cast once; GEMM2 emits
//     bf16 directly). Accumulate fp32. Quarter-wave x 16B/lane gather.

static constexpr int IN_DIM   = 128;
static constexpr int HID_DIM  = 256;
static constexpr int OUT_DIMC = 128;
static constexpr int NGROUP   = 8;   // = #XCDs on MI355X

typedef unsigned short ushort_t;
typedef unsigned int   uint_t;

static __device__ __forceinline__ ushort_t f2bf(float f) {   // RNE fp32->bf16
  uint_t u = __float_as_uint(f);
  uint_t r = (u + 0x7FFFu + ((u >> 16) & 1u)) >> 16;
  return (ushort_t)r;
}
static __device__ __forceinline__ float bflo(uint_t w) {      // low bf16 -> f32
  return __uint_as_float(w << 16);
}
static __device__ __forceinline__ float bfhi(uint_t w) {      // high bf16 -> f32
  return __uint_as_float(w & 0xFFFF0000u);
}

__global__ void k_zero_i32(int* __restrict__ p, int n) {
  int i = blockIdx.x * blockDim.x + threadIdx.x;
  if (i < n) p[i] = 0;
}

// fp32 -> bf16 table cast, 4 elems/thread
__global__ void k_cast_bf16(const float* __restrict__ in, ushort_t* __restrict__ outp,
                            int n4) {
  int i = blockIdx.x * blockDim.x + threadIdx.x;
  if (i < n4) {
    float4 v = ((const float4*)in)[i];
    ushort4 o;
    o.x = f2bf(v.x); o.y = f2bf(v.y); o.z = f2bf(v.z); o.w = f2bf(v.w);
    ((ushort4*)outp)[i] = o;
  }
}

// dst-range-partitioned histogram (group g = blockIdx&7 owns a node range)
__global__ void k_hist(const int* __restrict__ dst, int* __restrict__ cnt,
                       int E, int n) {
  int g = blockIdx.x & (NGROUP - 1);
  int b = blockIdx.x >> 3;
  int bpg = gridDim.x >> 3;
  int lo = (int)((long long)n * g / NGROUP);
  int hi = (int)((long long)n * (g + 1) / NGROUP);
  int stride = bpg * blockDim.x;
  for (int e = b * blockDim.x + threadIdx.x; e < E; e += stride) {
    int d = dst[e];
    if (d >= lo && d < hi) atomicAdd(&cnt[d], 1);
  }
}

__global__ void k_dis(const int* __restrict__ cnt, float* __restrict__ dis, int n) {
  int i = blockIdx.x * blockDim.x + threadIdx.x;
  if (i < n) dis[i] = rsqrtf((float)(cnt[i] + 1));  // +1 = self-loop
}

// ---- exclusive scan of cnt[] (chunk = 2048 = 256 thr x 8) ----
__global__ void k_chunksum(const int* __restrict__ cnt, int* __restrict__ csum, int n) {
  __shared__ int red[256];
  int tid = threadIdx.x;
  int base = blockIdx.x * 2048;
  int s = 0;
  for (int i = tid; i < 2048; i += 256) {
    int g = base + i;
    if (g < n) s += cnt[g];
  }
  red[tid] = s; __syncthreads();
  for (int off = 128; off > 0; off >>= 1) {
    if (tid < off) red[tid] += red[tid + off];
    __syncthreads();
  }
  if (tid == 0) csum[blockIdx.x] = red[0];
}

__global__ void k_scan_chunks(int* __restrict__ csum, int nchunks) {
  if (blockIdx.x == 0 && threadIdx.x == 0) {
    int acc = 0;
    for (int i = 0; i < nchunks; ++i) { int v = csum[i]; csum[i] = acc; acc += v; }
  }
}

__global__ void k_scan_final(const int* __restrict__ cnt, const int* __restrict__ csum,
                             int* __restrict__ rowp, int* __restrict__ cursor, int n) {
  __shared__ int lds[256];
  int tid = threadIdx.x;
  int gbase = blockIdx.x * 2048 + tid * 8;
  int loc[8]; int s = 0;
#pragma unroll
  for (int j = 0; j < 8; ++j) {
    int g = gbase + j;
    int v = (g < n) ? cnt[g] : 0;
    loc[j] = v; s += v;
  }
  lds[tid] = s; __syncthreads();
  for (int off = 1; off < 256; off <<= 1) {
    int add = (tid >= off) ? lds[tid - off] : 0;
    __syncthreads();
    lds[tid] += add;
    __syncthreads();
  }
  int run = csum[blockIdx.x] + lds[tid] - s;
#pragma unroll
  for (int j = 0; j < 8; ++j) {
    int g = gbase + j;
    if (g < n) { rowp[g] = run; cursor[g] = run; }
    run += loc[j];
  }
}

// dst-range-partitioned bucket scatter
__global__ void k_scatter(const int* __restrict__ src, const int* __restrict__ dst,
                          int* __restrict__ cursor, int* __restrict__ csr,
                          int E, int n) {
  int g = blockIdx.x & (NGROUP - 1);
  int b = blockIdx.x >> 3;
  int bpg = gridDim.x >> 3;
  int lo = (int)((long long)n * g / NGROUP);
  int hi = (int)((long long)n * (g + 1) / NGROUP);
  int stride = bpg * blockDim.x;
  for (int e = b * blockDim.x + threadIdx.x; e < E; e += stride) {
    int d = dst[e];
    if (d >= lo && d < hi) {
      int p = atomicAdd(&cursor[d], 1);
      csr[p] = src[e];
    }
  }
}

// ---- pull aggregation from a bf16 feature table, D=128.
// Quarter-wave layout: 16 lanes x 16B (uint4 = 8 bf16) cover one 256B row;
// 4 edges in flight per wave-iteration. fp32 accumulate (8 regs/lane),
// combine quarters via shfl_xor(16/32); quarter 0 writes fp32 row.
template<int D>
__global__ void k_agg_bf16(const ushort_t* __restrict__ feat, const float* __restrict__ dis,
                           const int* __restrict__ rowp, const int* __restrict__ cnt,
                           const int* __restrict__ csr, float* __restrict__ outp,
                           const float* __restrict__ bias, int n) {
  constexpr int Q = D / 8;               // uint4 (8 bf16) per row = 16 for D=128
  int wid = (blockIdx.x * blockDim.x + threadIdx.x) >> 6;
  if (wid >= n) return;
  const int lane    = threadIdx.x & 63;
  const int quarter = lane >> 4;         // 0..3: which edge of the quad
  const int ql      = lane & 15;         // uint4 index within row
  const int d       = wid;
  const float dd = dis[d];
  const int base = rowp[d];
  const int deg  = cnt[d];
  const uint4* f16 = (const uint4*)feat;

  float a0=0.f,a1=0.f,a2=0.f,a3=0.f,a4=0.f,a5=0.f,a6=0.f,a7=0.f;
  if (quarter == 0) {                    // self-loop term
    uint4 v = f16[(size_t)d * Q + ql];
    a0 = dd * bflo(v.x); a1 = dd * bfhi(v.x);
    a2 = dd * bflo(v.y); a3 = dd * bfhi(v.y);
    a4 = dd * bflo(v.z); a5 = dd * bfhi(v.z);
    a6 = dd * bflo(v.w); a7 = dd * bfhi(v.w);
  }

  for (int c = 0; c < deg; c += 64) {
    int idx = c + lane;
    int s_l = 0; float w_l = 0.f;
    if (idx < deg) { s_l = csr[base + idx]; w_l = dis[s_l]; }
    int m = deg - c; if (m > 64) m = 64;
    int quads = (m + 3) >> 2;            // lanes beyond m have w_l=0 -> safe
#pragma unroll 4
    for (int j = 0; j < quads; ++j) {
      int ei = 4 * j + quarter;
      int   sj = __shfl(s_l, ei);
      float wj = __shfl(w_l, ei);
      uint4 v = f16[(size_t)sj * Q + ql];
      a0 = fmaf(wj, bflo(v.x), a0); a1 = fmaf(wj, bfhi(v.x), a1);
      a2 = fmaf(wj, bflo(v.y), a2); a3 = fmaf(wj, bfhi(v.y), a3);
      a4 = fmaf(wj, bflo(v.z), a4); a5 = fmaf(wj, bfhi(v.z), a5);
      a6 = fmaf(wj, bflo(v.w), a6); a7 = fmaf(wj, bfhi(v.w), a7);
    }
  }

  // combine the four quarters' partials (same ql across quarters)
  a0 += __shfl_xor(a0, 16); a1 += __shfl_xor(a1, 16);
  a2 += __shfl_xor(a2, 16); a3 += __shfl_xor(a3, 16);
  a4 += __shfl_xor(a4, 16); a5 += __shfl_xor(a5, 16);
  a6 += __shfl_xor(a6, 16); a7 += __shfl_xor(a7, 16);
  a0 += __shfl_xor(a0, 32); a1 += __shfl_xor(a1, 32);
  a2 += __shfl_xor(a2, 32); a3 += __shfl_xor(a3, 32);
  a4 += __shfl_xor(a4, 32); a5 += __shfl_xor(a5, 32);
  a6 += __shfl_xor(a6, 32); a7 += __shfl_xor(a7, 32);

  if (quarter == 0) {
    a0 *= dd; a1 *= dd; a2 *= dd; a3 *= dd;
    a4 *= dd; a5 *= dd; a6 *= dd; a7 *= dd;
    if (bias) {
      const float4* b4 = (const float4*)bias;
      float4 blo = b4[ql * 2], bhi = b4[ql * 2 + 1];
      a0 += blo.x; a1 += blo.y; a2 += blo.z; a3 += blo.w;
      a4 += bhi.x; a5 += bhi.y; a6 += bhi.z; a7 += bhi.w;
    }
    float4* o4 = (float4*)(outp + (size_t)d * D + ql * 8);
    o4[0] = make_float4(a0, a1, a2, a3);
    o4[1] = make_float4(a4, a5, a6, a7);
  }
}

// ---- fp32 tiled GEMM: C[M,N] = A[M,K] @ B[K,N] (+bias, relu, opt bf16 out) ----
template<int K, bool RELU, bool BF16OUT>
__global__ __launch_bounds__(256) void k_gemm(const float* __restrict__ A,
                                              const float* __restrict__ B,
                                              const float* __restrict__ bias,
                                              void* __restrict__ C,
                                              int M, int N) {
  constexpr int BM = 64, BN = 64, BK = 32;
  __shared__ float As[BK][BM + 4];
  __shared__ float Bs[BK][BN];
  int colTiles = N >> 6;
  int bx = blockIdx.x % colTiles;
  int by = blockIdx.x / colTiles;
  int tid = threadIdx.x;
  int tx = tid & 15, ty = tid >> 4;
  int row0 = by * BM, col0 = bx * BN;
  float acc[4][4] = {};
  for (int k0 = 0; k0 < K; k0 += BK) {
#pragma unroll
    for (int i = 0; i < 2; ++i) {
      int t = tid + i * 256;
      int a_r = t >> 3;
      int a_c = (t & 7) << 2;
      int r = row0 + a_r;
      float4 v = make_float4(0.f, 0.f, 0.f, 0.f);
      if (r < M) v = *(const float4*)&A[(size_t)r * K + k0 + a_c];
      As[a_c + 0][a_r] = v.x;
      As[a_c + 1][a_r] = v.y;
      As[a_c + 2][a_r] = v.z;
      As[a_c + 3][a_r] = v.w;
    }
#pragma unroll
    for (int i = 0; i < 2; ++i) {
      int t = tid + i * 256;
      int b_r = t >> 4;
      int b_c = (t & 15) << 2;
      *(float4*)&Bs[b_r][b_c] = *(const float4*)&B[(size_t)(k0 + b_r) * N + col0 + b_c];
    }
    __syncthreads();
#pragma unroll
    for (int k = 0; k < BK; ++k) {
      float a[4], b[4];
#pragma unroll
      for (int i = 0; i < 4; ++i) a[i] = As[k][ty * 4 + i];
#pragma unroll
      for (int j = 0; j < 4; ++j) b[j] = Bs[k][tx * 4 + j];
#pragma unroll
      for (int i = 0; i < 4; ++i)
#pragma unroll
        for (int j = 0; j < 4; ++j)
          acc[i][j] = fmaf(a[i], b[j], acc[i][j]);
    }
    __syncthreads();
  }
  float bc[4] = {0.f, 0.f, 0.f, 0.f};
  if (bias) {
#pragma unroll
    for (int j = 0; j < 4; ++j) bc[j] = bias[col0 + tx * 4 + j];
  }
#pragma unroll
  for (int i = 0; i < 4; ++i) {
    int r = row0 + ty * 4 + i;
    if (r < M) {
      float v0 = acc[i][0] + bc[0];
      float v1 = acc[i][1] + bc[1];
      float v2 = acc[i][2] + bc[2];
      float v3 = acc[i][3] + bc[3];
      if (RELU) {
        v0 = fmaxf(v0, 0.f); v1 = fmaxf(v1, 0.f);
        v2 = fmaxf(v2, 0.f); v3 = fmaxf(v3, 0.f);
      }
      if (BF16OUT) {
        ushort4 o;
        o.x = f2bf(v0); o.y = f2bf(v1); o.z = f2bf(v2); o.w = f2bf(v3);
        *(ushort4*)&((ushort_t*)C)[(size_t)r * N + col0 + tx * 4] = o;
      } else {
        *(float4*)&((float*)C)[(size_t)r * N + col0 + tx * 4] =
            make_float4(v0, v1, v2, v3);
      }
    }
  }
}

extern "C" void kernel_launch(void* const* d_in, const int* in_sizes, int n_in,
                              void* d_out, int out_size, void* d_ws, size_t ws_size,
                              hipStream_t stream) {
  const float* x  = (const float*)d_in[0];
  const int*   ei = (const int*)d_in[1];
  const float* W1 = (const float*)d_in[2];
  const float* b1 = (const float*)d_in[3];
  const float* W2 = (const float*)d_in[4];
  const float* b2 = (const float*)d_in[5];
  float* out = (float*)d_out;

  const int n = in_sizes[0] / IN_DIM;
  const int E = in_sizes[1] / 2;
  const int* src = ei;
  const int* dst = ei + E;

  // workspace carve-up
  char* ws = (char*)d_ws;
  size_t off = 0;
  auto alloc = [&](size_t bytes) -> char* {
    char* p = ws + off;
    off = (off + bytes + 255) & ~size_t(255);
    return p;
  };
  int*     cnt    = (int*)    alloc((size_t)n * 4);
  int*     rowp   = (int*)    alloc((size_t)n * 4);
  int*     cursor = (int*)    alloc((size_t)n * 4);
  float*   dis    = (float*)  alloc((size_t)n * 4);
  int*     csum   = (int*)    alloc(4096);
  int*     csr    = (int*)    alloc((size_t)E * 4);
  float*   B1     = (float*)  alloc((size_t)n * IN_DIM * 4);   // aggx fp32; later hw-bf16 space
  float*   B2     = (float*)  alloc((size_t)n * HID_DIM * 4);  // h fp32
  ushort_t* xb    = (ushort_t*)alloc((size_t)n * IN_DIM * 2);  // x in bf16
  ushort_t* hwb   = (ushort_t*)B1;                             // reuse B1 for bf16 hw

  const int nb = (n + 255) / 256;
  const int nchunks = (n + 2047) / 2048;

  // ---- degree + dis + CSR build (dst-range partitioned, XCD-local) ----
  k_zero_i32<<<nb, 256, 0, stream>>>(cnt, n);
  k_cast_bf16<<<(n * IN_DIM / 4 + 255) / 256, 256, 0, stream>>>(x, xb, n * IN_DIM / 4);
  k_hist<<<2048, 256, 0, stream>>>(dst, cnt, E, n);
  k_dis<<<nb, 256, 0, stream>>>(cnt, dis, n);
  k_chunksum<<<nchunks, 256, 0, stream>>>(cnt, csum, n);
  k_scan_chunks<<<1, 1, 0, stream>>>(csum, nchunks);
  k_scan_final<<<nchunks, 256, 0, stream>>>(cnt, csum, rowp, cursor, n);
  k_scatter<<<2048, 256, 0, stream>>>(src, dst, cursor, csr, E, n);

  // ---- layer 1: agg(xb) -> B1 (fp32); B2 = relu(B1 @ W1 + b1) ----
  k_agg_bf16<IN_DIM><<<(n + 3) / 4, 256, 0, stream>>>(xb, dis, rowp, cnt, csr, B1, nullptr, n);
  {
    int rowTiles = (n + 63) / 64, colTiles = HID_DIM / 64;
    k_gemm<IN_DIM, true, false><<<rowTiles * colTiles, 256, 0, stream>>>(B1, W1, b1, B2, n, HID_DIM);
  }
  // ---- layer 2: hwb = bf16(B2 @ W2); out = agg(hwb) + b2 ----
  {
    int rowTiles = (n + 63) / 64, colTiles = OUT_DIMC / 64;
    k_gemm<HID_DIM, false, true><<<rowTiles * colTiles, 256, 0, stream>>>(B2, W2, nullptr, hwb, n, OUT_DIMC);
  }
  k_agg_bf16<OUT_DIMC><<<(n + 3) / 4, 256, 0, stream>>>(hwb, dis, rowp, cnt, csr, out, b2, n);
}